// Round 6
// baseline (1188.153 us; speedup 1.0000x reference)
//
#include <hip/hip_runtime.h>

typedef __attribute__((ext_vector_type(4))) float f32x4;
typedef __attribute__((ext_vector_type(8))) short s16x8;

#define MTOTW 65792   // 257*256: fp32 W stride per a-index

__device__ __forceinline__ short f2bf(float f) {
    unsigned u = __builtin_bit_cast(unsigned, f);
    u = (u + 0x7fffu + ((u >> 16) & 1u)) >> 16;   // RNE
    return (short)u;
}

// ---------- prep: l1,l2 -> bf16 (flat) ----------
__global__ __launch_bounds__(256) void conv_bf16(
    const float* __restrict__ a, const float* __restrict__ b,
    short* __restrict__ ao, short* __restrict__ bo)
{
    int i = blockIdx.x * 256 + threadIdx.x;
    const int HALF = 131072;
    float4 v; short* dst;
    if (i < HALF) { v = ((const float4*)a)[i]; dst = ao + (size_t)i * 4; }
    else          { v = ((const float4*)b)[i - HALF]; dst = bo + (size_t)(i - HALF) * 4; }
    short4 o; o.x = f2bf(v.x); o.y = f2bf(v.y); o.z = f2bf(v.z); o.w = f2bf(v.w);
    *(short4*)dst = o;
}

// ---------- prep: W3t[d][c] = bf16(W3[c][d]) ----------
__global__ __launch_bounds__(256) void prep_w3t(
    const float* __restrict__ W3, short* __restrict__ W3t)
{
    __shared__ float ld[32][33];
    int t = threadIdx.x, bx = blockIdx.x;
    int c0 = (bx >> 3) * 32, d0 = (bx & 7) * 32;
    int cr = t >> 3, dq = t & 7;
    float4 v = *(const float4*)&W3[(size_t)(c0 + cr) * 256 + d0 + dq * 4];
    ld[cr][dq*4+0] = v.x; ld[cr][dq*4+1] = v.y; ld[cr][dq*4+2] = v.z; ld[cr][dq*4+3] = v.w;
    __syncthreads();
    int dr = t >> 3, cq = t & 7;
    short4 o;
    o.x = f2bf(ld[cq*4+0][dr]); o.y = f2bf(ld[cq*4+1][dr]);
    o.z = f2bf(ld[cq*4+2][dr]); o.w = f2bf(ld[cq*4+3][dr]);
    *(short4*)&W3t[(size_t)(d0 + dr) * 256 + c0 + cq * 4] = o;
}

// ---------- prep: Wtp[c][a] = bf16(W[a][256][c]) ----------
__global__ __launch_bounds__(256) void prep_wtail(
    const float* __restrict__ W1, const float* __restrict__ W2,
    short* __restrict__ Wtp1, short* __restrict__ Wtp2)
{
    __shared__ float ld[32][33];
    int t = threadIdx.x, bx = blockIdx.x;
    const float* W = blockIdx.y ? W2 : W1;
    short* Wtp = blockIdx.y ? Wtp2 : Wtp1;
    int a0 = (bx >> 3) * 32, c0 = (bx & 7) * 32;
    int ar = t >> 3, cq = t & 7;
    float4 v = *(const float4*)&W[(size_t)(a0 + ar) * MTOTW + 65536 + c0 + cq * 4];
    ld[ar][cq*4+0] = v.x; ld[ar][cq*4+1] = v.y; ld[ar][cq*4+2] = v.z; ld[ar][cq*4+3] = v.w;
    __syncthreads();
    int cr = t >> 3, aq = t & 7;
    short4 o;
    o.x = f2bf(ld[aq*4+0][cr]); o.y = f2bf(ld[aq*4+1][cr]);
    o.z = f2bf(ld[aq*4+2][cr]); o.w = f2bf(ld[aq*4+3][cr]);
    *(short4*)&Wtp[(size_t)(c0 + cr) * 256 + a0 + aq * 4] = o;
}

// ---------- prep: Wp[c][b][a] = bf16(W[a][b][c]) ----------
__global__ __launch_bounds__(256) void prep_wp(
    const float* __restrict__ W1, const float* __restrict__ W2,
    short* __restrict__ Wp1, short* __restrict__ Wp2)
{
    __shared__ float ld[32][33];
    int t = threadIdx.x, bx = blockIdx.x;
    int b = blockIdx.y;
    const float* W = blockIdx.z ? W2 : W1;
    short* Wp = blockIdx.z ? Wp2 : Wp1;
    int a0 = (bx >> 3) * 32, c0 = (bx & 7) * 32;
    int ar = t >> 3, cq = t & 7;
    float4 v = *(const float4*)&W[(size_t)(a0 + ar) * MTOTW + (size_t)b * 256 + c0 + cq * 4];
    ld[ar][cq*4+0] = v.x; ld[ar][cq*4+1] = v.y; ld[ar][cq*4+2] = v.z; ld[ar][cq*4+3] = v.w;
    __syncthreads();
    int cr = t >> 3, aq = t & 7;
    short4 o;
    o.x = f2bf(ld[aq*4+0][cr]); o.y = f2bf(ld[aq*4+1][cr]);
    o.z = f2bf(ld[aq*4+2][cr]); o.w = f2bf(ld[aq*4+3][cr]);
    *(short4*)&Wp[((size_t)(c0 + cr) * 256 + b) * 256 + a0 + aq * 4] = o;
}

// ---------- tail_mfma: tail[r][c] = sum_{a<256} l1b[r][a]*Wtp[c][a] + W[256][256][c] ----------
__global__ __launch_bounds__(256, 2) void tail_mfma(
    const short* __restrict__ l1b,
    const short* __restrict__ Wtp1, const short* __restrict__ Wtp2,
    const float* __restrict__ W1, const float* __restrict__ W2,
    float* __restrict__ tail1, float* __restrict__ tail2)
{
    int t = threadIdx.x, w = t >> 6, lane = t & 63;
    int p = lane & 15, q = lane >> 4;
    int rt = blockIdx.x, nt = blockIdx.y, ten = blockIdx.z;
    const short* Wtp = ten ? Wtp2 : Wtp1;
    const float* Wf = ten ? W2 : W1;
    float* tail = ten ? tail2 : tail1;
    int m0w = (w >> 1) * 64, n0w = (w & 1) * 64;
    const short* Ab = l1b + (size_t)(rt * 128 + m0w + p) * 256 + q * 8;
    const short* Bb = Wtp + (size_t)(nt * 128 + n0w + p) * 256 + q * 8;

    f32x4 acc[4][4] = {};
    s16x8 af[2][4], bf[2][4];
    #pragma unroll
    for (int i = 0; i < 4; ++i) {
        af[0][i] = *(const s16x8*)(Ab + (size_t)i * 16 * 256);
        bf[0][i] = *(const s16x8*)(Bb + (size_t)i * 16 * 256);
    }
    #pragma unroll
    for (int ks = 0; ks < 8; ++ks) {
        int cur = ks & 1;
        if (ks < 7) {
            #pragma unroll
            for (int i = 0; i < 4; ++i) {
                af[cur ^ 1][i] = *(const s16x8*)(Ab + (ks + 1) * 32 + (size_t)i * 16 * 256);
                bf[cur ^ 1][i] = *(const s16x8*)(Bb + (ks + 1) * 32 + (size_t)i * 16 * 256);
            }
        }
        #pragma unroll
        for (int mi = 0; mi < 4; ++mi)
            #pragma unroll
            for (int ni = 0; ni < 4; ++ni)
                acc[mi][ni] = __builtin_amdgcn_mfma_f32_16x16x32_bf16(af[cur][mi], bf[cur][ni], acc[mi][ni], 0, 0, 0);
    }
    #pragma unroll
    for (int ni = 0; ni < 4; ++ni) {
        int c = nt * 128 + n0w + ni * 16 + p;
        float tl = Wf[(size_t)256 * MTOTW + 65536 + c];
        #pragma unroll
        for (int mi = 0; mi < 4; ++mi) {
            int r = rt * 128 + m0w + mi * 16 + q * 4;
            #pragma unroll
            for (int reg = 0; reg < 4; ++reg)
                tail[(size_t)(r + reg) * 256 + c] = acc[mi][ni][reg] + tl;
        }
    }
}

// ---------- stage1: T[rl][c][b] = bf16( sum_a l1b[r][a]*Wp[c][b][a] + W[256][b][c] ) ----------
__global__ __launch_bounds__(256, 3) void stage1(
    const short* __restrict__ l1b,
    const short* __restrict__ Wp1, const short* __restrict__ Wp2,
    const float* __restrict__ W1, const float* __restrict__ W2,
    short* __restrict__ T1, short* __restrict__ T2, int row0)
{
    __shared__ __align__(16) short Cep[4 * 4096];
    int t = threadIdx.x, w = t >> 6, lane = t & 63;
    int p = lane & 15, q = lane >> 4;
    int rt = blockIdx.x, bt = blockIdx.y, zc = blockIdx.z;
    int c = zc >> 1, ten = zc & 1;
    const short* Wp = ten ? Wp2 : Wp1;
    const float* Wf = ten ? W2 : W1;
    short* T = ten ? T2 : T1;
    int r0g = row0 + rt * 128;
    int b0 = bt * 128;
    int m0w = (w >> 1) * 64, n0w = (w & 1) * 64;
    const short* Ab = l1b + (size_t)(r0g + m0w + p) * 256 + q * 8;
    const short* Bb = Wp + ((size_t)c * 256 + b0 + n0w + p) * 256 + q * 8;

    f32x4 acc[4][4] = {};
    s16x8 af[2][4], bf[2][4];
    #pragma unroll
    for (int i = 0; i < 4; ++i) {
        af[0][i] = *(const s16x8*)(Ab + (size_t)i * 16 * 256);
        bf[0][i] = *(const s16x8*)(Bb + (size_t)i * 16 * 256);
    }
    #pragma unroll
    for (int ks = 0; ks < 8; ++ks) {
        int cur = ks & 1;
        if (ks < 7) {
            #pragma unroll
            for (int i = 0; i < 4; ++i) {
                af[cur ^ 1][i] = *(const s16x8*)(Ab + (ks + 1) * 32 + (size_t)i * 16 * 256);
                bf[cur ^ 1][i] = *(const s16x8*)(Bb + (ks + 1) * 32 + (size_t)i * 16 * 256);
            }
        }
        #pragma unroll
        for (int mi = 0; mi < 4; ++mi)
            #pragma unroll
            for (int ni = 0; ni < 4; ++ni)
                acc[mi][ni] = __builtin_amdgcn_mfma_f32_16x16x32_bf16(af[cur][mi], bf[cur][ni], acc[mi][ni], 0, 0, 0);
    }

    short* Cw = &Cep[w * 4096];
    #pragma unroll
    for (int ni = 0; ni < 4; ++ni) {
        int b = b0 + n0w + ni * 16 + p;
        float tl = Wf[(size_t)256 * MTOTW + (size_t)b * 256 + c];
        #pragma unroll
        for (int mi = 0; mi < 4; ++mi)
            #pragma unroll
            for (int reg = 0; reg < 4; ++reg)
                Cw[(mi * 16 + q * 4 + reg) * 64 + ni * 16 + p] = f2bf(acc[mi][ni][reg] + tl);
    }
    #pragma unroll
    for (int s = 0; s < 8; ++s) {
        int row = s * 8 + (lane >> 3);
        int co = (lane & 7) * 8;
        int rl = rt * 128 + m0w + row;
        int gb = b0 + n0w + co;
        *(int4*)&T[((size_t)rl * 256 + c) * 256 + gb] = *(int4*)&Cw[row * 64 + co];
    }
}

// ---------- stage2: Al staged once; direct-global B frags; barrier-free K loops ----------
__global__ __launch_bounds__(256, 2) void stage2(
    const short* __restrict__ l2b,
    const short* __restrict__ T1, const short* __restrict__ T2,
    const float* __restrict__ tail1, const float* __restrict__ tail2,
    const float* __restrict__ h1, const float* __restrict__ h2,
    const short* __restrict__ W3t, float* __restrict__ out, int row0)
{
    __shared__ __align__(16) short Al[64 * 264];   // l2 j-tile, full K, padded rows
    __shared__ __align__(16) short V1[64 * 264];
    __shared__ float part[64 * 4];
    int t = threadIdx.x, w = t >> 6, lane = t & 63;
    int p = lane & 15, q = lane >> 4;
    int jt = blockIdx.x, rl = blockIdx.y;
    int rg = row0 + rl, n = rg >> 8, j0 = jt * 64;
    int n0w = w * 64;

    // stage Al once: 64 rows x 512 B; each thread copies 64 shorts (8 x int4)
    {
        int j = t >> 2, seg = t & 3;
        const short* src = l2b + ((size_t)n * 256 + j0 + j) * 256 + seg * 64;
        short* dst = &Al[j * 264 + seg * 64];
        #pragma unroll
        for (int x = 0; x < 8; ++x)      // FIX: was x < 4 (half of each row was garbage)
            *(int4*)(dst + x * 8) = *(const int4*)(src + x * 8);
    }
    __syncthreads();

    // ---- phase A: U1,U2 with direct-global T fragments ----
    const short* Bb1 = T1 + (size_t)rl * 65536 + (size_t)(n0w + p) * 256 + q * 8;
    const short* Bb2 = T2 + (size_t)rl * 65536 + (size_t)(n0w + p) * 256 + q * 8;
    f32x4 acc1[4][4] = {}, acc2[4][4] = {};
    {
        s16x8 b1f[2][4], b2f[2][4];
        #pragma unroll
        for (int i = 0; i < 4; ++i) {
            b1f[0][i] = *(const s16x8*)(Bb1 + (size_t)i * 16 * 256);
            b2f[0][i] = *(const s16x8*)(Bb2 + (size_t)i * 16 * 256);
        }
        #pragma unroll
        for (int ks = 0; ks < 8; ++ks) {
            int cur = ks & 1;
            if (ks < 7) {
                #pragma unroll
                for (int i = 0; i < 4; ++i) {
                    b1f[cur ^ 1][i] = *(const s16x8*)(Bb1 + (ks + 1) * 32 + (size_t)i * 16 * 256);
                    b2f[cur ^ 1][i] = *(const s16x8*)(Bb2 + (ks + 1) * 32 + (size_t)i * 16 * 256);
                }
            }
            s16x8 af[4];
            #pragma unroll
            for (int i = 0; i < 4; ++i)
                af[i] = *(const s16x8*)&Al[(i * 16 + p) * 264 + ks * 32 + q * 8];
            #pragma unroll
            for (int mi = 0; mi < 4; ++mi)
                #pragma unroll
                for (int ni = 0; ni < 4; ++ni) {
                    acc1[mi][ni] = __builtin_amdgcn_mfma_f32_16x16x32_bf16(af[mi], b1f[cur][ni], acc1[mi][ni], 0, 0, 0);
                    acc2[mi][ni] = __builtin_amdgcn_mfma_f32_16x16x32_bf16(af[mi], b2f[cur][ni], acc2[mi][ni], 0, 0, 0);
                }
        }
    }

    // V1 = h1*(U1+tail1) -> LDS bf16 ; v2 = h2*(U2+tail2) -> regs
    f32x4 v2[4][4];
    #pragma unroll
    for (int ni = 0; ni < 4; ++ni) {
        int c = n0w + ni * 16 + p;
        float hh1 = h1[(size_t)rg * 256 + c], tl1 = tail1[(size_t)rg * 256 + c];
        float hh2 = h2[(size_t)rg * 256 + c], tl2 = tail2[(size_t)rg * 256 + c];
        #pragma unroll
        for (int mi = 0; mi < 4; ++mi)
            #pragma unroll
            for (int reg = 0; reg < 4; ++reg) {
                V1[(mi * 16 + q * 4 + reg) * 264 + c] = f2bf(hh1 * (acc1[mi][ni][reg] + tl1));
                v2[mi][ni][reg] = hh2 * (acc2[mi][ni][reg] + tl2);
            }
    }
    __syncthreads();

    // ---- phase B: P = V1 @ W3t^T, W3 frags direct-global ----
    const short* Bb3 = W3t + (size_t)(n0w + p) * 256 + q * 8;
    f32x4 accP[4][4] = {};
    {
        s16x8 wf[2][4];
        #pragma unroll
        for (int i = 0; i < 4; ++i)
            wf[0][i] = *(const s16x8*)(Bb3 + (size_t)i * 16 * 256);
        #pragma unroll
        for (int ks = 0; ks < 8; ++ks) {
            int cur = ks & 1;
            if (ks < 7) {
                #pragma unroll
                for (int i = 0; i < 4; ++i)
                    wf[cur ^ 1][i] = *(const s16x8*)(Bb3 + (ks + 1) * 32 + (size_t)i * 16 * 256);
            }
            s16x8 af[4];
            #pragma unroll
            for (int i = 0; i < 4; ++i)
                af[i] = *(const s16x8*)&V1[(i * 16 + p) * 264 + ks * 32 + q * 8];
            #pragma unroll
            for (int mi = 0; mi < 4; ++mi)
                #pragma unroll
                for (int ni = 0; ni < 4; ++ni)
                    accP[mi][ni] = __builtin_amdgcn_mfma_f32_16x16x32_bf16(af[mi], wf[cur][ni], accP[mi][ni], 0, 0, 0);
        }
    }

    // out[j] = sum_d P[j][d] * V2[j][d]
    #pragma unroll
    for (int mi = 0; mi < 4; ++mi)
        #pragma unroll
        for (int reg = 0; reg < 4; ++reg) {
            float s = 0.f;
            #pragma unroll
            for (int ni = 0; ni < 4; ++ni) s += accP[mi][ni][reg] * v2[mi][ni][reg];
            s += __shfl_xor(s, 1); s += __shfl_xor(s, 2);
            s += __shfl_xor(s, 4); s += __shfl_xor(s, 8);
            if (p == 0)
                part[(mi * 16 + q * 4 + reg) * 4 + w] = s;
        }
    __syncthreads();
    if (t < 64)
        out[(size_t)rg * 256 + j0 + t] = part[t*4] + part[t*4+1] + part[t*4+2] + part[t*4+3];
}

extern "C" void kernel_launch(void* const* d_in, const int* in_sizes, int n_in,
                              void* d_out, int out_size, void* d_ws, size_t ws_size,
                              hipStream_t stream) {
    const float* layer1 = (const float*)d_in[0];
    const float* layer2 = (const float*)d_in[1];
    const float* h1     = (const float*)d_in[2];
    const float* h2     = (const float*)d_in[3];
    const float* W1     = (const float*)d_in[4];
    const float* W2     = (const float*)d_in[5];
    const float* W3     = (const float*)d_in[6];
    float* out = (float*)d_out;

    short* Wp1  = (short*)d_ws;
    short* Wp2  = Wp1 + 16777216;
    short* l1b  = Wp2 + 16777216;
    short* l2b  = l1b + 524288;
    short* W3t  = l2b + 524288;
    short* Wtp1 = W3t + 65536;
    short* Wtp2 = Wtp1 + 65536;
    float* tail1 = (float*)(Wtp2 + 65536);
    float* tail2 = tail1 + 524288;
    short* T1   = (short*)(tail2 + 524288);
    const size_t head = (size_t)(16777216*2 + 524288*2 + 65536*3) * 2 + (size_t)524288 * 2 * 4;
    int chunk = 2048;
    while (head + (size_t)chunk * 262144 > ws_size && chunk > 128) chunk >>= 1;
    short* T2 = T1 + (size_t)chunk * 65536;

    conv_bf16<<<1024, 256, 0, stream>>>(layer1, layer2, l1b, l2b);
    prep_w3t<<<64, 256, 0, stream>>>(W3, W3t);
    prep_wtail<<<dim3(64, 2), 256, 0, stream>>>(W1, W2, Wtp1, Wtp2);
    prep_wp<<<dim3(64, 256, 2), 256, 0, stream>>>(W1, W2, Wp1, Wp2);
    tail_mfma<<<dim3(16, 2, 2), 256, 0, stream>>>(l1b, Wtp1, Wtp2, W1, W2, tail1, tail2);

    for (int row0 = 0; row0 < 2048; row0 += chunk) {
        stage1<<<dim3(chunk / 128, 2, 512), 256, 0, stream>>>(
            l1b, Wp1, Wp2, W1, W2, T1, T2, row0);
        stage2<<<dim3(4, chunk), 256, 0, stream>>>(
            l2b, T1, T2, tail1, tail2, h1, h2, W3t, out, row0);
    }
}